// Round 1
// baseline (140.067 us; speedup 1.0000x reference)
//
#include <hip/hip_runtime.h>
#include <stdint.h>

// MultiHeadAttention: B=1024, F=128, D=128, H=8, dh=16, fp32 in/out.
// Fused per-batch kernel: proj (Q,K,V in LDS bf16, R in regs) -> swapped-QK^T
// attention (lane-local softmax) -> PV + residual -> fp32 out.

typedef __attribute__((ext_vector_type(8))) short short8;
typedef __attribute__((ext_vector_type(4))) float f32x4;
typedef __attribute__((ext_vector_type(16))) float f32x16;
typedef unsigned short ushort_t;
typedef unsigned int uint_t;

#define QS_OFF 0        // Qs[h][f][e] bf16, row-swizzled          (32 KiB)
#define KS_OFF 32768    // Ks[h][f][e] bf16                        (32 KiB)
#define VT_OFF 65536    // Vt[h][e][f] bf16, e-swizzled            (32 KiB)
#define XP_OFF 98304    // phase1/2: Xs[128][128]; phase3: Ps[w][32][128] (32 KiB)
#define LDS_BYTES 131072

__device__ __forceinline__ ushort_t bf16r(float f) {  // RNE fp32->bf16
  uint_t u = __float_as_uint(f);
  u += 0x7fffu + ((u >> 16) & 1u);
  return (ushort_t)(u >> 16);
}
__device__ __forceinline__ float bf2f(ushort_t b) {
  return __uint_as_float(((uint_t)b) << 16);
}

// Q/K: byte = base + h*4096 + f'*32 + e*2 with row permute f' = f ^ ((f>>2)&3)
// -> conflict-free b16 epilogue stores (G4-style swizzle).
__device__ __forceinline__ int qk_byte(int base, int h, int f, int e2) {
  int fr = f ^ ((f >> 2) & 3);
  return base + h * 4096 + fr * 32 + e2;
}
// X / P tiles: [row][128 cols bf16], stride 256B -> XOR bits 4-6 (T2 st-swizzle)
__device__ __forceinline__ int x_byte(int row, int colb) {
  return XP_OFF + row * 256 + (colb ^ ((row & 7) << 4));
}
__device__ __forceinline__ int vt_byte(int h, int e, int fb) {
  return VT_OFF + h * 4096 + e * 256 + (fb ^ ((e & 7) << 4));
}
__device__ __forceinline__ int ps_byte(int w, int row, int kb) {
  return XP_OFF + w * 8192 + row * 256 + (kb ^ ((row & 7) << 4));
}

// ---------------- prep: weights fp32 -> bf16 in MFMA-B-fragment order -------
// wt layout: unit u = p*32 + n*4 + kk  (p=proj, n=N-tile of 16 cols, kk=K-step
// of 32). Within unit: lane l (0..63) holds 8 bf16 = W[k0..k0+7][col],
// col = 16n + (l&15), k0 = (l>>4)*8 + 32kk. -> main-kernel B loads are
// lane-contiguous global_load_dwordx4.
__global__ void prep_w(const float* __restrict__ Wq, const float* __restrict__ Wk,
                       const float* __restrict__ Wv, const float* __restrict__ Wr,
                       ushort_t* __restrict__ wt) {
  int i = blockIdx.x * 256 + threadIdx.x;  // 65536 total
  int u = i >> 9;
  int l = (i >> 3) & 63;
  int j = i & 7;
  int p = u >> 5, n = (u >> 2) & 7, kk = u & 3;
  int col = n * 16 + (l & 15);
  int k = ((l >> 4) & 3) * 8 + kk * 32 + j;
  const float* W = (p == 0) ? Wq : (p == 1) ? Wk : (p == 2) ? Wv : Wr;
  wt[i] = bf16r(W[k * 128 + col]);
}

// ---------------- helpers --------------------------------------------------
__device__ __forceinline__ void proj_accum(const short8 (&afr)[2][4],
                                           const short8* __restrict__ wfr,
                                           int P, int l, f32x4 (&acc)[2][8]) {
#pragma unroll
  for (int n = 0; n < 8; ++n)
#pragma unroll
    for (int kk = 0; kk < 4; ++kk) {
      short8 bfr = wfr[(P * 32 + n * 4 + kk) * 64 + l];
#pragma unroll
      for (int m = 0; m < 2; ++m)
        acc[m][n] = __builtin_amdgcn_mfma_f32_16x16x32_bf16(afr[m][kk], bfr,
                                                            acc[m][n], 0, 0, 0);
    }
}

__device__ __forceinline__ void zero_acc(f32x4 (&acc)[2][8]) {
#pragma unroll
  for (int m = 0; m < 2; ++m)
#pragma unroll
    for (int n = 0; n < 8; ++n) acc[m][n] = (f32x4){0.f, 0.f, 0.f, 0.f};
}

__device__ __forceinline__ void store_qk(char* lds, int base, int w, int l,
                                         const f32x4 (&acc)[2][8]) {
  int g4 = ((l >> 4) & 3) * 4;
#pragma unroll
  for (int n = 0; n < 8; ++n)
#pragma unroll
    for (int m = 0; m < 2; ++m)
#pragma unroll
      for (int r = 0; r < 4; ++r) {
        int f = 32 * w + 16 * m + g4 + r;  // D-layout: row=(l>>4)*4+r, col=l&15
        *(ushort_t*)(lds + qk_byte(base, n, f, (l & 15) * 2)) = bf16r(acc[m][n][r]);
      }
}

// ---------------- main fused kernel ----------------------------------------
__global__ __launch_bounds__(256, 1) void mha_fused(const float* __restrict__ X,
                                                    const ushort_t* __restrict__ wt,
                                                    float* __restrict__ out) {
  extern __shared__ char lds[];
  const int b = blockIdx.x;
  const int t = threadIdx.x;
  const int w = t >> 6;       // wave 0..3, owns query rows [32w, 32w+32)
  const int l = t & 63;

  // ---- Phase 1: stage X[b] (fp32) -> Xs (bf16, swizzled), coalesced ----
  const float4* Xb = (const float4*)(X + (size_t)b * (128 * 128));
#pragma unroll
  for (int i = 0; i < 16; ++i) {
    int idx = i * 256 + t;           // lane-contiguous float4 loads
    float4 v = Xb[idx];
    int row = idx >> 5;
    int c4 = idx & 31;
    uint_t lo = (uint_t)bf16r(v.x) | ((uint_t)bf16r(v.y) << 16);
    uint_t hi = (uint_t)bf16r(v.z) | ((uint_t)bf16r(v.w) << 16);
    *(uint2*)(lds + x_byte(row, c4 * 8)) = make_uint2(lo, hi);
  }
  __syncthreads();

  // ---- Phase 2: projections (one A-frag set serves Q,K,V,R) ----
  const int lr = l & 15;                 // A row within 16-tile
  const int lkb = ((l >> 4) & 3) * 16;   // byte offset of k0=(l>>4)*8
  short8 afr[2][4];
#pragma unroll
  for (int m = 0; m < 2; ++m)
#pragma unroll
    for (int kk = 0; kk < 4; ++kk) {
      int row = 32 * w + 16 * m + lr;
      afr[m][kk] = *(const short8*)(lds + x_byte(row, lkb + 64 * kk));
    }

  const short8* wfr = (const short8*)wt;
  f32x4 acc[2][8];

  zero_acc(acc);
  proj_accum(afr, wfr, 0, l, acc);   // Q
  store_qk(lds, QS_OFF, w, l, acc);

  zero_acc(acc);
  proj_accum(afr, wfr, 1, l, acc);   // K
  store_qk(lds, KS_OFF, w, l, acc);

  zero_acc(acc);
  proj_accum(afr, wfr, 2, l, acc);   // V -> Vt[h][e][f] (packed 8B stores)
  {
    int g4 = ((l >> 4) & 3) * 4;
#pragma unroll
    for (int n = 0; n < 8; ++n)
#pragma unroll
      for (int m = 0; m < 2; ++m) {
        int f0 = 32 * w + 16 * m + g4;
        uint_t lo = (uint_t)bf16r(acc[m][n][0]) | ((uint_t)bf16r(acc[m][n][1]) << 16);
        uint_t hi = (uint_t)bf16r(acc[m][n][2]) | ((uint_t)bf16r(acc[m][n][3]) << 16);
        *(uint2*)(lds + vt_byte(n, l & 15, f0 * 2)) = make_uint2(lo, hi);
      }
  }

  f32x4 Racc[2][8];                  // residual projection stays in registers
  zero_acc(Racc);
  proj_accum(afr, wfr, 3, l, Racc);

  __syncthreads();  // Q/K/V visible; Xs region becomes Ps scratch

  // ---- Phase 3: attention (no barriers; waves independent) ----
  const float cexp = 0.12751459f;  // (1/sqrt(128)) * log2(e)
  const int q = l & 31;            // local query row (wave-owned)
  const int hi5 = l >> 5;
  const int e0b = hi5 * 16;        // e0*2 bytes, e0=(l>>5)*8

#pragma unroll
  for (int h = 0; h < 8; ++h) {
    // S^T = K_h (A) x Q_h^T (B): 32x32x16, K-dim = dh = 16, one MFMA per tile.
    short8 qf = *(const short8*)(lds + qk_byte(QS_OFF, h, 32 * w + q, e0b));
    f32x16 st[4];
#pragma unroll
    for (int tt = 0; tt < 4; ++tt) {
      short8 kf = *(const short8*)(lds + qk_byte(KS_OFF, h, 32 * tt + q, e0b));
      f32x16 z = {0.f, 0.f, 0.f, 0.f, 0.f, 0.f, 0.f, 0.f,
                  0.f, 0.f, 0.f, 0.f, 0.f, 0.f, 0.f, 0.f};
      st[tt] = __builtin_amdgcn_mfma_f32_32x32x16_bf16(kf, qf, z, 0, 0, 0);
    }
    // lane-local softmax over k (64 values here + complement in lane^32)
    float mx = st[0][0];
#pragma unroll
    for (int tt = 0; tt < 4; ++tt)
#pragma unroll
      for (int r = 0; r < 16; ++r) mx = fmaxf(mx, st[tt][r]);
    mx = fmaxf(mx, __shfl_xor(mx, 32, 64));
    float cm = cexp * mx;
    float sum = 0.f;
#pragma unroll
    for (int tt = 0; tt < 4; ++tt) {
#pragma unroll
      for (int u = 0; u < 4; ++u) {
        ushort_t pb[4];
#pragma unroll
        for (int v = 0; v < 4; ++v) {  // k = 32tt + 8u + 4hi + v (consecutive)
          float p = exp2f(cexp * st[tt][4 * u + v] - cm);
          pb[v] = bf16r(p);
          sum += bf2f(pb[v]);          // normalize by sum of ROUNDED weights
        }
        uint_t lo = (uint_t)pb[0] | ((uint_t)pb[1] << 16);
        uint_t hi2 = (uint_t)pb[2] | ((uint_t)pb[3] << 16);
        int k0 = 32 * tt + 8 * u + 4 * hi5;
        *(uint2*)(lds + ps_byte(w, q, k0 * 2)) = make_uint2(lo, hi2);
      }
    }
    sum += __shfl_xor(sum, 32, 64);
    float rcp = 1.0f / sum;

    // O = P x V_h : 16x16x32, A = P (row-major LDS), B = V^T rows (contiguous)
    f32x4 oacc[2] = {{0.f, 0.f, 0.f, 0.f}, {0.f, 0.f, 0.f, 0.f}};
#pragma unroll
    for (int kk = 0; kk < 4; ++kk) {
      short8 vf = *(const short8*)(lds + vt_byte(h, l & 15, lkb + 64 * kk));
#pragma unroll
      for (int m = 0; m < 2; ++m) {
        int row = 16 * m + lr;
        short8 pf = *(const short8*)(lds + ps_byte(w, row, lkb + 64 * kk));
        oacc[m] = __builtin_amdgcn_mfma_f32_16x16x32_bf16(pf, vf, oacc[m], 0, 0, 0);
      }
    }
    // epilogue: normalize, add in-register residual, write fp32
    int g4 = ((l >> 4) & 3) * 4;
#pragma unroll
    for (int m = 0; m < 2; ++m)
#pragma unroll
      for (int r = 0; r < 4; ++r) {
        int fl = 16 * m + g4 + r;              // 0..31, == P/O row == R row
        float rc = __shfl(rcp, fl, 64);        // lane fl holds sum for q=fl
        float val = oacc[m][r] * rc + Racc[m][h][r];
        int f = 32 * w + fl;
        out[((size_t)b * 128 + f) * 128 + 16 * h + (l & 15)] = val;
      }
  }
}

extern "C" void kernel_launch(void* const* d_in, const int* in_sizes, int n_in,
                              void* d_out, int out_size, void* d_ws, size_t ws_size,
                              hipStream_t stream) {
  const float* X  = (const float*)d_in[0];
  const float* Wq = (const float*)d_in[1];
  const float* Wk = (const float*)d_in[2];
  const float* Wv = (const float*)d_in[3];
  const float* Wr = (const float*)d_in[4];
  float* out = (float*)d_out;
  ushort_t* wt = (ushort_t*)d_ws;  // 128 KiB of fragment-ordered bf16 weights

  hipLaunchKernelGGL(prep_w, dim3(256), dim3(256), 0, stream, Wq, Wk, Wv, Wr, wt);
  hipLaunchKernelGGL(mha_fused, dim3(1024), dim3(256), LDS_BYTES, stream, X, wt, out);
}

// Round 3
// 114.853 us; speedup vs baseline: 1.2195x; 1.2195x over previous
//
#include <hip/hip_runtime.h>
#include <hip/hip_bf16.h>
#include <stdint.h>

// MHA B=1024,F=128,D=128,H=8,dh=16 fp32. Round 3: R2 structure, inline asm
// removed (cvt_pk asm -> __float2bfloat16; permlane32_swap -> shfl_xor+select
// with corrected orientation). 2048 blocks = (batch, head-half); 256 thr;
// 48 KiB LDS -> 3 blocks/CU. All MFMA 32x32x16 bf16.

typedef __attribute__((ext_vector_type(8))) short short8;
typedef __attribute__((ext_vector_type(16))) float f32x16;
typedef __attribute__((ext_vector_type(4))) unsigned int uint4v;
typedef __attribute__((ext_vector_type(2))) unsigned int uint2v;
typedef unsigned short ushort_t;
typedef unsigned int uint_t;

#define KF_OFF 0        // Kfrag[4h][4tt][64lane][16B]   (16 KiB)
#define QF_OFF 16384    // Qfrag[4h][4tt][64lane][16B]   (16 KiB)
#define VT_OFF 32768    // Vt[4h][16e][128f] bf16, e-swizzled (16 KiB)

__device__ __forceinline__ ushort_t b16(float f) {  // RNE via HIP intrinsic
  __hip_bfloat16 h = __float2bfloat16(f);
  return __builtin_bit_cast(ushort_t, h);
}
__device__ __forceinline__ uint_t pk2(float a, float b) {  // {lo:a, hi:b}
  return (uint_t)b16(a) | ((uint_t)b16(b) << 16);
}

// ---- prep: weights fp32 -> bf16, 32x32x16 B-fragment order ----------------
// unit u = (p*4 + np)*8 + kk ; lane l, elem j holds W_p[kk*16+(l>>5)*8+j][32np+(l&31)]
__global__ void prep_w(const float* __restrict__ Wq, const float* __restrict__ Wk,
                       const float* __restrict__ Wv, const float* __restrict__ Wr,
                       ushort_t* __restrict__ wt) {
  int i = blockIdx.x * 256 + threadIdx.x;  // 65536 total
  int u = i >> 9;
  int l = (i >> 3) & 63;
  int j = i & 7;
  int p = u >> 5, np = (u >> 3) & 3, kk = u & 7;
  int col = 32 * np + (l & 31);
  int d = kk * 16 + ((l >> 5) & 1) * 8 + j;
  const float* W = (p == 0) ? Wq : (p == 1) ? Wk : (p == 2) ? Wv : Wr;
  wt[i] = b16(W[d * 128 + col]);
}

// ---- main fused kernel -----------------------------------------------------
__global__ __launch_bounds__(256, 3) void mha3(const float* __restrict__ X,
                                               const ushort_t* __restrict__ wt,
                                               float* __restrict__ out) {
  __shared__ char lds[49152];
  const int t = threadIdx.x;
  const int w = t >> 6, l = t & 63;
  const int i = blockIdx.x;
  // XCD-pair swizzle: both head-halves of a batch share i%8 (same XCD),
  // dispatched 8 apart (co-resident) -> duplicate X reads hit L2.
  const int b = (i & 7) * 128 + (i >> 4);
  const int bh = (i >> 3) & 1;
  const int hi5 = l >> 5, q = l & 31, e = l & 15, hb = (l >> 4) & 1;

  // ---- A-fragments: wave's 32 X-rows direct from global, fp32 -> bf16 ----
  const float* xrow = X + (((size_t)b * 128) + 32 * w + q) * 128;
  short8 afr[8];
#pragma unroll
  for (int kk = 0; kk < 8; ++kk) {
    float4 a = *(const float4*)(xrow + kk * 16 + 8 * hi5);
    float4 c4 = *(const float4*)(xrow + kk * 16 + 8 * hi5 + 4);
    uint4v u = {pk2(a.x, a.y), pk2(a.z, a.w), pk2(c4.x, c4.y), pk2(c4.z, c4.w)};
    afr[kk] = __builtin_bit_cast(short8, u);
  }

  const short8* wf = (const short8*)wt;
  auto proj = [&](int p, int n) {
    f32x16 acc = {};
#pragma unroll
    for (int kk = 0; kk < 8; ++kk) {
      short8 bfr = wf[((p * 4 + 2 * bh + n) * 8 + kk) * 64 + l];
      acc = __builtin_amdgcn_mfma_f32_32x32x16_bf16(afr[kk], bfr, acc, 0, 0, 0);
    }
    return acc;
  };
  // D (col=32n+(l&31), rows=(r&3)+8*(r>>2)+4*hi5 in wave tile w) -> fragment
  // order: elem (f,e) -> tile w, slot (f&31)+32*(e>>3), byte (e&7)*2
  auto st_qk = [&](int off, int n, const f32x16& d) {
    char* p = lds + off + (2 * n + hb) * 4096 + w * 1024 + 512 * (e >> 3) +
              (e & 7) * 2 + 64 * hi5;
#pragma unroll
    for (int r = 0; r < 16; ++r) {
      int o16 = ((r & 3) + 8 * (r >> 2)) * 16;
      *(ushort_t*)(p + o16) = b16(d[r]);
    }
  };
  auto st_v = [&](int n, const f32x16& d) {  // transposed Vt[e][f], packed 8B
    int hl = 2 * n + hb;
#pragma unroll
    for (int q2 = 0; q2 < 4; ++q2) {
      int f0 = 32 * w + 8 * q2 + 4 * hi5;
      uint2v pk = {pk2(d[4 * q2 + 0], d[4 * q2 + 1]),
                   pk2(d[4 * q2 + 2], d[4 * q2 + 3])};
      *(uint2v*)(lds + VT_OFF + hl * 4096 + e * 256 +
                 ((f0 * 2) ^ ((e & 7) << 4))) = pk;
    }
  };

  f32x16 Ra[2];
  {
    f32x16 d;
    d = proj(0, 0); st_qk(QF_OFF, 0, d);
    d = proj(0, 1); st_qk(QF_OFF, 1, d);
    d = proj(1, 0); st_qk(KF_OFF, 0, d);
    d = proj(1, 1); st_qk(KF_OFF, 1, d);
    d = proj(2, 0); st_v(0, d);
    d = proj(2, 1); st_v(1, d);
    Ra[0] = proj(3, 0);
    Ra[1] = proj(3, 1);
  }
  __syncthreads();  // only barrier: Q/K/V visible to all waves

  // ---- attention: 4 local heads, waves independent, no barriers ----
  const float cexp = 0.12751459f;  // (1/sqrt(128)) * log2(e)
#pragma unroll
  for (int n = 0; n < 2; ++n) {
    f32x16 o2[2];
#pragma unroll
    for (int hp = 0; hp < 2; ++hp) {
      int h = 2 * n + hp;
      // S^T tile = K(A) x Q^T(B); D col = query (lane-local softmax)
      short8 qf = *(const short8*)(lds + QF_OFF + h * 4096 + w * 1024 + l * 16);
      f32x16 s4[4];
#pragma unroll
      for (int tt = 0; tt < 4; ++tt) {
        short8 kf = *(const short8*)(lds + KF_OFF + h * 4096 + tt * 1024 + l * 16);
        f32x16 z = {};
        s4[tt] = __builtin_amdgcn_mfma_f32_32x32x16_bf16(kf, qf, z, 0, 0, 0);
      }
      // max over 64 own values (log-depth) + partner lane
      f32x16 mv = __builtin_elementwise_max(
          __builtin_elementwise_max(s4[0], s4[1]),
          __builtin_elementwise_max(s4[2], s4[3]));
#pragma unroll
      for (int s = 8; s >= 1; s >>= 1)
#pragma unroll
        for (int r = 0; r < s; ++r) mv[r] = fmaxf(mv[r], mv[r + s]);
      float mx = fmaxf(mv[0], __shfl_xor(mv[0], 32, 64));
      float cm = cexp * mx;
#pragma unroll
      for (int tt = 0; tt < 4; ++tt)
#pragma unroll
        for (int r = 0; r < 16; ++r)
          s4[tt][r] = exp2f(__builtin_fmaf(cexp, s4[tt][r], -cm));
      f32x16 sv = (s4[0] + s4[1]) + (s4[2] + s4[3]);
#pragma unroll
      for (int s = 8; s >= 1; s >>= 1)
#pragma unroll
        for (int r = 0; r < s; ++r) sv[r] += sv[r + s];
      float sum = sv[0] + __shfl_xor(sv[0], 32, 64);
      float rs = 1.0f / sum;

      // P (normalized bf16) in-register. Own packed words per 16-key group g:
      //  lo lane: wl={k0,k1} wl2={k2,k3} wh={k8,k9}   wh2={k10,k11}
      //  hi lane: wl={k4,k5} wl2={k6,k7} wh={k12,k13} wh2={k14,k15}
      // A-frag needs lo: {k0..k7} = {wl,wl2,swl,swl2};
      //              hi: {k8..k15} = {swh,swh2,wh,wh2}  (s* = partner l^32)
      f32x16 o = {};
#pragma unroll
      for (int g = 0; g < 8; ++g) {
        int tt = g >> 1, rb = (g & 1) * 8;
        uint_t wl  = pk2(s4[tt][rb + 0] * rs, s4[tt][rb + 1] * rs);
        uint_t wl2 = pk2(s4[tt][rb + 2] * rs, s4[tt][rb + 3] * rs);
        uint_t wh  = pk2(s4[tt][rb + 4] * rs, s4[tt][rb + 5] * rs);
        uint_t wh2 = pk2(s4[tt][rb + 6] * rs, s4[tt][rb + 7] * rs);
        uint_t swl  = (uint_t)__shfl_xor((int)wl, 32, 64);
        uint_t swl2 = (uint_t)__shfl_xor((int)wl2, 32, 64);
        uint_t swh  = (uint_t)__shfl_xor((int)wh, 32, 64);
        uint_t swh2 = (uint_t)__shfl_xor((int)wh2, 32, 64);
        uint4v pw;
        pw[0] = hi5 ? swh : wl;
        pw[1] = hi5 ? swh2 : wl2;
        pw[2] = hi5 ? wh : swl;
        pw[3] = hi5 ? wh2 : swl2;
        short8 pa = __builtin_bit_cast(short8, pw);
        // B = V rows (keys) x cols (e), duplicated across both 16-col halves
        short8 vfr = *(const short8*)(lds + VT_OFF + h * 4096 + e * 256 +
                                      ((32 * g + 16 * hi5) ^ ((e & 7) << 4)));
        o = __builtin_amdgcn_mfma_f32_32x32x16_bf16(pa, vfr, o, 0, 0, 0);
      }
      o2[hp] = o;
    }
    // epilogue: O D-layout == R D-layout -> register residual add
#pragma unroll
    for (int r = 0; r < 16; ++r) {
      float ov = hb ? o2[1][r] : o2[0][r];
      float val = ov + Ra[n][r];
      int f = 32 * w + (r & 3) + 8 * (r >> 2) + 4 * hi5;
      int col = 64 * bh + 32 * n + q;
      out[((size_t)b * 128 + f) * 128 + col] = val;
    }
  }
}

extern "C" void kernel_launch(void* const* d_in, const int* in_sizes, int n_in,
                              void* d_out, int out_size, void* d_ws, size_t ws_size,
                              hipStream_t stream) {
  const float* X  = (const float*)d_in[0];
  const float* Wq = (const float*)d_in[1];
  const float* Wk = (const float*)d_in[2];
  const float* Wv = (const float*)d_in[3];
  const float* Wr = (const float*)d_in[4];
  float* out = (float*)d_out;
  ushort_t* wt = (ushort_t*)d_ws;  // 128 KiB fragment-ordered bf16 weights

  hipLaunchKernelGGL(prep_w, dim3(256), dim3(256), 0, stream, Wq, Wk, Wv, Wr, wt);
  hipLaunchKernelGGL(mha3, dim3(2048), dim3(256), 0, stream, X, wt, out);
}